// Round 1
// baseline (9.455 us; speedup 1.0000x reference)
//
#include <hip/hip_runtime.h>

// out[b] = 2*x[b, N-1] - x[b, N-2], for B rows of N fp32 each.
// One thread per row; aligned float2 load of the last two columns.
__global__ void interp_pred_kernel(const float* __restrict__ x,
                                   float* __restrict__ out,
                                   int B, int N) {
    int b = blockIdx.x * blockDim.x + threadIdx.x;
    if (b >= B) return;
    // last two elements: offsets N-2, N-1. (N-2)*4 bytes is 8-aligned when N even.
    const float2 v = *reinterpret_cast<const float2*>(x + (size_t)b * N + (N - 2));
    out[b] = 2.0f * v.y - v.x;
}

extern "C" void kernel_launch(void* const* d_in, const int* in_sizes, int n_in,
                              void* d_out, int out_size, void* d_ws, size_t ws_size,
                              hipStream_t stream) {
    const float* x = (const float*)d_in[0];
    float* out = (float*)d_out;
    const int N = 2048;
    const int B = in_sizes[0] / N;   // 131072
    const int block = 256;
    const int grid = (B + block - 1) / block;
    interp_pred_kernel<<<grid, block, 0, stream>>>(x, out, B, N);
}